// Round 9
// baseline (411.276 us; speedup 1.0000x reference)
//
#include <hip/hip_runtime.h>
#include <hip/hip_bf16.h>

// ---- problem constants (fixed by the reference) ----
#define HS   1024
#define FF   4096
#define NH   16
#define HD   64
#define SEQ  2048
#define BSZ  2
#define MROWS (BSZ * SEQ)   // 4096 token rows
#define EPS  1e-5f
#define QKV_STRIDE (3 * HS) // fused qkv activation row stride

typedef float f32x4  __attribute__((ext_vector_type(4)));
typedef short bf16x8 __attribute__((ext_vector_type(8)));

__device__ __forceinline__ unsigned short f2bf(float x) {
  unsigned int u = __float_as_uint(x);
  u += 0x7fffu + ((u >> 16) & 1u);   // round-to-nearest-even
  return (unsigned short)(u >> 16);
}

// pack two floats -> packed bf16 pair (low = a, high = b)
__device__ __forceinline__ unsigned int pkbf(float a, float b) {
  union { __hip_bfloat162 h; unsigned int u; } x;
  x.h = __float22bfloat162_rn(float2{a, b});
  return x.u;
}

// async global->LDS, 16 B per lane; LDS dest = wave-uniform base + lane*16
__device__ __forceinline__ void async16(const ushort* g, ushort* lds) {
  __builtin_amdgcn_global_load_lds(
      (const __attribute__((address_space(1))) unsigned int*)g,
      (__attribute__((address_space(3))) unsigned int*)lds, 16, 0, 0);
}

// ======================================================================
// bf16 MFMA GEMM (m97 structure), templated tile + optional split-K:
//   C[M,N] = A[M,K] @ B[K,N] (+bias unless PARTIAL), Bt = B^T [N][K]
// TBMxTBN tile, BK=64, 256 thr = 4 waves (2x2). blockIdx.z = k-slice of
// length kLen. PARTIAL: f32 partial slab at Cout + z*zstride (explicit
// stride — slabs need NOT be adjacent; bias deferred to the reduce).
// ======================================================================
template <int TBM, int TBN, bool RELU, bool OUT_BF16, bool PARTIAL>
__global__ __launch_bounds__(256) void gemm_bf16_kernel(
    const ushort* __restrict__ A, const ushort* __restrict__ Bt,
    const float* __restrict__ bias, void* __restrict__ Cout,
    int M, int N, int K, int kLen, size_t zstride)
{
  constexpr int MI = TBM / 32;
  constexpr int NJ = TBN / 32;
  __shared__ ushort As[TBM * 64];
  __shared__ ushort Bs[TBN * 64];

  const int tid = threadIdx.x;
  const int wv = tid >> 6, ln = tid & 63;
  const int bn = blockIdx.x, bm = blockIdx.y;

  const int lr = ln & 15;
  const int lg = ln >> 4;
  const int mrow_base = (wv >> 1) * (TBM / 2);
  const int ncol_base = (wv & 1) * (TBN / 2);

  f32x4 acc[MI][NJ];
#pragma unroll
  for (int i = 0; i < MI; ++i)
#pragma unroll
    for (int j = 0; j < NJ; ++j) acc[i][j] = (f32x4){0.f, 0.f, 0.f, 0.f};

  const int rr = ln >> 3, cc = ln & 7;
  const int kBeg = blockIdx.z * kLen, kEnd = kBeg + kLen;

  for (int k0 = kBeg; k0 < kEnd; k0 += 64) {
    __syncthreads();
#pragma unroll
    for (int t = 0; t < TBM / 32; ++t) {
      const int R = wv * (TBM / 4) + t * 8 + rr;
      const int c = cc ^ (R & 7);
      async16(A + (size_t)(bm * TBM + R) * K + k0 + c * 8,
              &As[(size_t)(wv * (TBM / 4) + t * 8) * 64]);
    }
#pragma unroll
    for (int t = 0; t < TBN / 32; ++t) {
      const int R = wv * (TBN / 4) + t * 8 + rr;
      const int c = cc ^ (R & 7);
      async16(Bt + (size_t)(bn * TBN + R) * K + k0 + c * 8,
              &Bs[(size_t)(wv * (TBN / 4) + t * 8) * 64]);
    }
    __syncthreads();

#pragma unroll
    for (int s = 0; s < 2; ++s) {
      bf16x8 a[MI], b[NJ];
#pragma unroll
      for (int i = 0; i < MI; ++i) {
        const int m = mrow_base + i * 16 + lr;
        a[i] = *(const bf16x8*)&As[(size_t)m * 64 + (((s * 4 + lg) ^ (m & 7)) * 8)];
      }
#pragma unroll
      for (int j = 0; j < NJ; ++j) {
        const int n = ncol_base + j * 16 + lr;
        b[j] = *(const bf16x8*)&Bs[(size_t)n * 64 + (((s * 4 + lg) ^ (n & 7)) * 8)];
      }
#pragma unroll
      for (int i = 0; i < MI; ++i)
#pragma unroll
        for (int j = 0; j < NJ; ++j)
          acc[i][j] = __builtin_amdgcn_mfma_f32_16x16x32_bf16(a[i], b[j], acc[i][j], 0, 0, 0);
    }
  }

  const int gm0 = bm * TBM + mrow_base;
  const int gn0 = bn * TBN + ncol_base;

  if (PARTIAL) {
    float* Cp = (float*)Cout + (size_t)blockIdx.z * zstride;
#pragma unroll
    for (int i = 0; i < MI; ++i)
#pragma unroll
      for (int r = 0; r < 4; ++r) {
        const size_t row = (size_t)(gm0 + i * 16 + lg * 4 + r);
#pragma unroll
        for (int j = 0; j < NJ; ++j)
          Cp[row * N + gn0 + j * 16 + lr] = acc[i][j][r];
      }
  } else {
    float bs4[NJ];
#pragma unroll
    for (int j = 0; j < NJ; ++j) bs4[j] = bias[gn0 + j * 16 + lr];
    float* Cf = (float*)Cout;
    ushort* Cb = (ushort*)Cout;
#pragma unroll
    for (int i = 0; i < MI; ++i) {
#pragma unroll
      for (int r = 0; r < 4; ++r) {
        const size_t row = (size_t)(gm0 + i * 16 + lg * 4 + r);
#pragma unroll
        for (int j = 0; j < NJ; ++j) {
          float val = acc[i][j][r] + bs4[j];
          if (RELU) val = fmaxf(val, 0.f);
          const size_t idx = row * N + gn0 + j * 16 + lr;
          if (OUT_BF16) Cb[idx] = f2bf(val);
          else          Cf[idx] = val;
        }
      }
    }
  }
}

// ======================================================================
// Fused prep kernel: 6 weight transposes (fp32 [K][N] -> bf16 [N][K]),
// bias concat, x -> bf16.  One launch, 5121 blocks.
// ======================================================================
__device__ __forceinline__ void transpose_tile(
    const float* __restrict__ W, ushort* __restrict__ Wt,
    int K, int N, int n0, int k0, int tid, ushort (*T)[72])
{
#pragma unroll
  for (int t = 0; t < 4; ++t) {
    const int r = t * 16 + (tid >> 4);
    const int c = (tid & 15) * 4;
    const float4 w = *(const float4*)&W[(size_t)(k0 + r) * N + n0 + c];
    T[c + 0][r] = f2bf(w.x); T[c + 1][r] = f2bf(w.y);
    T[c + 2][r] = f2bf(w.z); T[c + 3][r] = f2bf(w.w);
  }
  __syncthreads();
#pragma unroll
  for (int t = 0; t < 4; ++t) {
    const int n = t * 16 + (tid >> 4);
    const int kc = (tid & 15) * 4;
    ushort4 o;
    o.x = T[n][kc]; o.y = T[n][kc + 1]; o.z = T[n][kc + 2]; o.w = T[n][kc + 3];
    *(ushort4*)&Wt[(size_t)(n0 + n) * K + k0 + kc] = o;
  }
}

__global__ __launch_bounds__(256) void prep_kernel(
    const float* __restrict__ Wq, const float* __restrict__ Wk,
    const float* __restrict__ Wv, const float* __restrict__ Wo,
    const float* __restrict__ W1, const float* __restrict__ W2,
    const float* __restrict__ bq, const float* __restrict__ bk,
    const float* __restrict__ bv, const float* __restrict__ x,
    ushort* __restrict__ Wqkvt, ushort* __restrict__ Wot,
    ushort* __restrict__ W1t, ushort* __restrict__ W2t,
    float* __restrict__ bqkv, ushort* __restrict__ xb)
{
  __shared__ ushort T[64][72];
  const int b = blockIdx.x, tid = threadIdx.x;
  const size_t M1 = 1024 * 1024;
  if (b < 1024) {              // Wq/Wk/Wv/Wo: 256 tiles each
    const int w = b >> 8, l = b & 255;
    const int n0 = (l & 15) * 64, k0 = (l >> 4) * 64;
    const float* src = (w == 0) ? Wq : (w == 1) ? Wk : (w == 2) ? Wv : Wo;
    ushort* dst = (w < 3) ? (Wqkvt + (size_t)w * M1) : Wot;
    transpose_tile(src, dst, HS, HS, n0, k0, tid, T);
  } else if (b < 2048) {       // W1 [1024][4096] -> W1t [4096][1024]
    const int l = b - 1024;
    transpose_tile(W1, W1t, HS, FF, (l & 63) * 64, (l >> 6) * 64, tid, T);
  } else if (b < 3072) {       // W2 [4096][1024] -> W2t [1024][4096]
    const int l = b - 2048;
    transpose_tile(W2, W2t, FF, HS, (l & 15) * 64, (l >> 4) * 64, tid, T);
  } else if (b < 5120) {       // x -> bf16, 2048 elems per block
    const size_t base = (size_t)(b - 3072) * 2048 + tid * 8;
    const float4 v0 = *(const float4*)&x[base];
    const float4 v1 = *(const float4*)&x[base + 4];
    ushort4 o0, o1;
    o0.x = f2bf(v0.x); o0.y = f2bf(v0.y); o0.z = f2bf(v0.z); o0.w = f2bf(v0.w);
    o1.x = f2bf(v1.x); o1.y = f2bf(v1.y); o1.z = f2bf(v1.z); o1.w = f2bf(v1.w);
    *(ushort4*)&xb[base] = o0;
    *(ushort4*)&xb[base + 4] = o1;
  } else {                     // bias concat
#pragma unroll
    for (int t = 0; t < 12; ++t) {
      const int i = t * 256 + tid;
      bqkv[i] = (i < HS) ? bq[i] : (i < 2 * HS) ? bk[i - HS] : bv[i - 2 * HS];
    }
  }
}

// ======================================================================
// vb bf16 [token][stride] -> VTg bf16 [(b,h,d)][seq]
// ======================================================================
__global__ __launch_bounds__(256) void vtrans_kernel(
    const ushort* __restrict__ vb, ushort* __restrict__ VTg, int stride)
{
  __shared__ ushort T[64][68];
  const int tid = threadIdx.x;
  const int s0 = blockIdx.x * 64;
  const int bh = blockIdx.y;
  const int b = bh >> 4, h = bh & 15;
#pragma unroll
  for (int t = 0; t < 4; ++t) {
    const int rr = t * 16 + (tid >> 4);
    const int c4 = (tid & 15) * 4;
    const ushort4 w = *(const ushort4*)&vb[(size_t)(b * SEQ + s0 + rr) * stride + h * 64 + c4];
    T[c4 + 0][rr] = w.x; T[c4 + 1][rr] = w.y;
    T[c4 + 2][rr] = w.z; T[c4 + 3][rr] = w.w;
  }
  __syncthreads();
#pragma unroll
  for (int t = 0; t < 4; ++t) {
    const int d = t * 16 + (tid >> 4);
    const int k4 = (tid & 15) * 4;
    ushort4 o;
    o.x = T[d][k4]; o.y = T[d][k4 + 1]; o.z = T[d][k4 + 2]; o.w = T[d][k4 + 3];
    *(ushort4*)&VTg[((size_t)bh * 64 + d) * SEQ + s0 + k4] = o;
  }
}

// ======================================================================
// MFMA flash attention, KB=128 (16 iters). 128 thr = 2 waves x 64 q:
// each wave owns FOUR 16-q fragments -> kf/vf LDS reads amortized over
// 4 q-frags: 48 b128 reads per 128 MFMA per iter (r8: 40 per 64).
// Per-CU LDS cycles ~49k vs r8's 74k — attention is LDS-throughput-bound
// (r7/r8 post-mortems). S^T processed in two 64-key halves to bound
// register pressure (as_ = 16 f32x4 live). Unnormalized softmax
// (p = exp(min(s,60)), lane-local l, reduced once at the end).
// P per-wave-private (no extra barrier).
// LDS: K 16K + VT 16K + P 2x16K = 64 KB -> 2 blocks/CU (grid 512).
// ======================================================================
__global__ __launch_bounds__(128, 1) void attention_mfma_kernel(
    const ushort* __restrict__ Qb, const ushort* __restrict__ Kb,
    const ushort* __restrict__ VTg, const float* __restrict__ mask,
    ushort* __restrict__ O)
{
  __shared__ ushort smem[32768];          // 64 KB
  ushort* Ks  = smem;                     // [128 key][64 d]
  ushort* VTs = smem + 8192;              // [64 d][128 key]
  ushort* Ps  = smem + 16384;             // 2 x [64 q][128 key]

  const int tid = threadIdx.x;
  const int wv = tid >> 6, ln = tid & 63;
  const int c = ln & 15, g = ln >> 4;
  const int qt = blockIdx.x, hh = blockIdx.y, b = blockIdx.z;
  const int bh = b * NH + hh;
  const size_t row0 = (size_t)b * SEQ + (size_t)qt * 128;
  const int ch = hh * HD;
  const int wq0 = wv * 64;

  // persistent Q fragments: qf[nt][s] = Q[q=wq0+nt*16+c][d=s*32+g*8 ..+7]
  bf16x8 qf[4][2];
#pragma unroll
  for (int nt = 0; nt < 4; ++nt)
#pragma unroll
    for (int s = 0; s < 2; ++s)
      qf[nt][s] = *(const bf16x8*)&Qb[(row0 + wq0 + nt * 16 + c) * QKV_STRIDE + ch + s * 32 + g * 8];

  f32x4 ao[4][4];                         // [mt=d-tile][nt=q-frag]
#pragma unroll
  for (int i = 0; i < 4; ++i)
#pragma unroll
    for (int j = 0; j < 4; ++j) ao[i][j] = (f32x4){0, 0, 0, 0};
  float l_r[4] = {0.f, 0.f, 0.f, 0.f};

  ushort* Pw = Ps + wv * 8192;            // this wave's private P (64q x 128k)
  const int rr = ln >> 3, cc = ln & 7;    // K staging coords (8 lanes/row)
  const int r4 = ln >> 4, sc = ln & 15;   // VT staging coords (16 lanes/row)

  for (int kb = 0; kb < SEQ / 128; ++kb) {
    __syncthreads();
    const size_t krow0 = (size_t)b * SEQ + (size_t)kb * 128;
    // stage K: 128 rows x 128 B; wave wv covers rows wv*64 .. +63
#pragma unroll
    for (int t = 0; t < 8; ++t) {
      const int r = wv * 64 + t * 8 + rr;
      async16(Kb + (krow0 + r) * QKV_STRIDE + ch + ((cc ^ (r & 7)) * 8),
              &Ks[(size_t)(wv * 64 + t * 8) * 64]);
    }
    // stage V^T: 64 rows x 256 B; wave wv covers rows wv*32 .. +31
#pragma unroll
    for (int t = 0; t < 8; ++t) {
      const int d = wv * 32 + t * 4 + r4;
      const int srcc = (sc & 8) | ((sc & 7) ^ (d & 7));
      async16(VTg + ((size_t)bh * 64 + d) * SEQ + kb * 128 + srcc * 8,
              &VTs[(size_t)(wv * 32 + t * 4) * 128]);
    }
    __syncthreads();

    // ---- S^T = K @ Q^T in two 64-key halves (register pressure) ----
#pragma unroll
    for (int half = 0; half < 2; ++half) {
      f32x4 as_[4][4];                    // [mt over 64 keys][nt]
#pragma unroll
      for (int i = 0; i < 4; ++i)
#pragma unroll
        for (int j = 0; j < 4; ++j) as_[i][j] = (f32x4){0, 0, 0, 0};
#pragma unroll
      for (int s = 0; s < 2; ++s) {
#pragma unroll
        for (int mt = 0; mt < 4; ++mt) {
          const int key = half * 64 + mt * 16 + c;
          const bf16x8 kf = *(const bf16x8*)&Ks[(size_t)key * 64 + (((s * 4 + g) ^ (key & 7)) * 8)];
#pragma unroll
          for (int nt = 0; nt < 4; ++nt)
            as_[mt][nt] = __builtin_amdgcn_mfma_f32_16x16x32_bf16(kf, qf[nt][s], as_[mt][nt], 0, 0, 0);
        }
      }

      // p = exp(min(s*scale + mask, 60)); lane-local sums per nt
#pragma unroll
      for (int mt = 0; mt < 4; ++mt) {
        const float4 mk = *(const float4*)&mask[(size_t)b * SEQ + kb * 128 + half * 64 + mt * 16 + g * 4];
        const float mka[4] = {mk.x, mk.y, mk.z, mk.w};
#pragma unroll
        for (int nt = 0; nt < 4; ++nt) {
#pragma unroll
          for (int r = 0; r < 4; ++r) {
            const float p = __expf(fminf(as_[mt][nt][r] * 0.125f + mka[r], 60.f));
            as_[mt][nt][r] = p;
            l_r[nt] += p;
          }
        }
      }

      // P -> LDS (bf16, chunk-swizzled, 8B stores), per-wave private
#pragma unroll
      for (int mt = 0; mt < 4; ++mt) {
        const int kc = 2 * (half * 4 + mt) + (g >> 1);
        const int slot = (kc & 8) | ((kc & 7) ^ (c & 7));
#pragma unroll
        for (int nt = 0; nt < 4; ++nt) {
          const int q = nt * 16 + c;
          const int base = q * 128 + slot * 8 + 4 * (g & 1);
          uint2 w;
          w.x = pkbf(as_[mt][nt][0], as_[mt][nt][1]);
          w.y = pkbf(as_[mt][nt][2], as_[mt][nt][3]);
          *(uint2*)&Pw[base] = w;
        }
      }
    }

    // ---- O^T += V^T @ P^T ----
#pragma unroll
    for (int s = 0; s < 4; ++s) {
      const int k = s * 4 + g;
      bf16x8 pf[4];
#pragma unroll
      for (int nt = 0; nt < 4; ++nt) {
        const int q = nt * 16 + c;
        const int pslot = (k & 8) | ((k & 7) ^ (q & 7));
        pf[nt] = *(const bf16x8*)&Pw[(size_t)q * 128 + pslot * 8];
      }
#pragma unroll
      for (int mt = 0; mt < 4; ++mt) {
        const int d = mt * 16 + c;
        const int vslot = (k & 8) | ((k & 7) ^ (d & 7));
        const bf16x8 vf = *(const bf16x8*)&VTs[(size_t)d * 128 + vslot * 8];
#pragma unroll
        for (int nt = 0; nt < 4; ++nt)
          ao[mt][nt] = __builtin_amdgcn_mfma_f32_16x16x32_bf16(vf, pf[nt], ao[mt][nt], 0, 0, 0);
      }
    }
  }

  // final denominators: reduce over the 4 g-groups (same q = col c)
#pragma unroll
  for (int nt = 0; nt < 4; ++nt) {
    l_r[nt] += __shfl_xor(l_r[nt], 16, 64);
    l_r[nt] += __shfl_xor(l_r[nt], 32, 64);
  }

  // epilogue: transpose O^T -> O via LDS, coalesced bf16 store
  __syncthreads();
  ushort* OL = smem;                      // [128 q][72]
#pragma unroll
  for (int nt = 0; nt < 4; ++nt) {
    const float inv = 1.f / l_r[nt];
    const int q = wq0 + nt * 16 + c;
#pragma unroll
    for (int mt = 0; mt < 4; ++mt) {
      const int d = mt * 16 + g * 4;
      uint2 w;
      w.x = pkbf(ao[mt][nt][0] * inv, ao[mt][nt][1] * inv);
      w.y = pkbf(ao[mt][nt][2] * inv, ao[mt][nt][3] * inv);
      *(uint2*)&OL[q * 72 + d] = w;
    }
  }
  __syncthreads();
#pragma unroll
  for (int it = 0; it < 8; ++it) {
    const int unit = it * 128 + tid;      // 1024 units of 16 B
    const int q = unit >> 3, sg = unit & 7;
    const uint4 w = *(const uint4*)&OL[q * 72 + sg * 8];
    *(uint4*)&O[(row0 + q) * HS + ch + sg * 8] = w;
  }
}

// ======================================================================
// out = LayerNorm(X + P0 + P1 + bias) * g + b  (split-K reduce fused)
// ======================================================================
template <bool EMIT16>
__global__ __launch_bounds__(256) void add_ln_red_kernel(
    const float* __restrict__ P0, const float* __restrict__ P1,
    const float* __restrict__ bias, const float* __restrict__ X,
    const float* __restrict__ g, const float* __restrict__ b,
    float* __restrict__ out, ushort* __restrict__ outb)
{
  const int row = blockIdx.x;
  const int tid = threadIdx.x;
  const size_t base = (size_t)row * HS + tid * 4;
  const float4 p0 = *(const float4*)&P0[base];
  const float4 p1 = *(const float4*)&P1[base];
  const float4 bi = *(const float4*)&bias[tid * 4];
  const float4 xv = *(const float4*)&X[base];
  float4 v;
  v.x = xv.x + p0.x + p1.x + bi.x;
  v.y = xv.y + p0.y + p1.y + bi.y;
  v.z = xv.z + p0.z + p1.z + bi.z;
  v.w = xv.w + p0.w + p1.w + bi.w;
  float s1 = v.x + v.y + v.z + v.w;
  float s2 = v.x * v.x + v.y * v.y + v.z * v.z + v.w * v.w;
#pragma unroll
  for (int off = 32; off > 0; off >>= 1) {
    s1 += __shfl_down(s1, off, 64);
    s2 += __shfl_down(s2, off, 64);
  }
  __shared__ float red[8];
  __shared__ float stat[2];
  const int wid = tid >> 6;
  if ((tid & 63) == 0) { red[wid] = s1; red[4 + wid] = s2; }
  __syncthreads();
  if (tid == 0) {
    const float t1 = red[0] + red[1] + red[2] + red[3];
    const float t2 = red[4] + red[5] + red[6] + red[7];
    const float mean = t1 * (1.f / HS);
    const float var = t2 * (1.f / HS) - mean * mean;
    stat[0] = mean;
    stat[1] = rsqrtf(var + EPS);
  }
  __syncthreads();
  const float mean = stat[0], rstd = stat[1];
  const float4 gv = *(const float4*)&g[tid * 4];
  const float4 bv = *(const float4*)&b[tid * 4];
  float4 r;
  r.x = (v.x - mean) * rstd * gv.x + bv.x;
  r.y = (v.y - mean) * rstd * gv.y + bv.y;
  r.z = (v.z - mean) * rstd * gv.z + bv.z;
  r.w = (v.w - mean) * rstd * gv.w + bv.w;
  *(float4*)&out[base] = r;
  if (EMIT16) {
    ushort4 o;
    o.x = f2bf(r.x); o.y = f2bf(r.y); o.z = f2bf(r.z); o.w = f2bf(r.w);
    *(ushort4*)&outb[base] = o;
  }
}

// ======================================================================
// Orchestration. Arena (ushort units, M1 = 1M ush = 2 MB), hw 94 MB:
//  0-3M   Wqkvt  (dead after QKV)    -> ff2P0 f32 0-8M  (at FF2)
//  3-4M   Wot    (dead after Wo GEMM)
//  4-8M   W1t    (dead after FF1)
//  8-12M  W2t    [live through FF2 — ff2 slab1 must NOT touch]
//  12-13M bqkv f32
//  13-17M xb     (dead after QKV)   -> woP slab0 f32 13-21M (at Wo)
//  17-29M qkvb   (dead after attn)  -> woP slab1 f32 21-29M; ff1o bf16 13-29M
//  29-33M VTg    (dead after attn)  -> h f32 29-37M (at ln1)
//  33-37M attnb  (dead after Wo)
//  37-39M hb bf16 (at ln1)
//  39-47M ff2P1 f32 (at FF2)        [separate slab via zstride]
// ======================================================================
extern "C" void kernel_launch(void* const* d_in, const int* in_sizes, int n_in,
                              void* d_out, int out_size, void* d_ws, size_t ws_size,
                              hipStream_t stream)
{
  const float* x    = (const float*)d_in[0];
  const float* mask = (const float*)d_in[1];
  const float* Wq   = (const float*)d_in[2];  const float* bq  = (const float*)d_in[3];
  const float* Wk   = (const float*)d_in[4];  const float* bk  = (const float*)d_in[5];
  const float* Wv   = (const float*)d_in[6];  const float* bv  = (const float*)d_in[7];
  const float* Wo   = (const float*)d_in[8];  const float* bo  = (const float*)d_in[9];
  const float* W1   = (const float*)d_in[10]; const float* b1  = (const float*)d_in[11];
  const float* W2   = (const float*)d_in[12]; const float* b2  = (const float*)d_in[13];
  const float* g1   = (const float*)d_in[14]; const float* be1 = (const float*)d_in[15];
  const float* g2   = (const float*)d_in[16]; const float* be2 = (const float*)d_in[17];
  float* out = (float*)d_out;

  ushort* wsu = (ushort*)d_ws;
  const size_t M1 = 1024 * 1024;

  ushort* Wqkvt = wsu;
  ushort* Wot   = wsu + 3 * M1;
  ushort* W1t   = wsu + 4 * M1;
  ushort* W2t   = wsu + 8 * M1;
  float*  bqkv  = (float*)(wsu + 12 * M1);
  ushort* xb    = wsu + 13 * M1;
  ushort* qkvb  = wsu + 17 * M1;            // [4096][3072]
  ushort* VTg   = wsu + 29 * M1;
  ushort* attnb = wsu + 33 * M1;
  float*  woP   = (float*)(wsu + 13 * M1);  // 2 adjacent 4M-f32 slabs 13-29M
  float*  h     = (float*)(wsu + 29 * M1);  // aliases VTg+attnb (dead)
  ushort* hb    = wsu + 37 * M1;
  ushort* ff1o  = wsu + 13 * M1;            // [4096][4096] (woP dead)
  float*  ff2P0 = (float*)wsu;              // 0-8M (Wqkvt/Wot/W1t dead)
  float*  ff2P1 = (float*)(wsu + 39 * M1);  // 39-47M (clears W2t + ff1o)

  const dim3 blk(256);
  const size_t SLAB = (size_t)MROWS * HS;   // 4M elements

  prep_kernel<<<dim3(5121), blk, 0, stream>>>(
      Wq, Wk, Wv, Wo, W1, W2, bq, bk, bv, x,
      Wqkvt, Wot, W1t, W2t, bqkv, xb);

  gemm_bf16_kernel<128, 128, false, true, false><<<dim3(24, 32), blk, 0, stream>>>(
      xb, Wqkvt, bqkv, qkvb, MROWS, 3 * HS, HS, HS, 0);

  vtrans_kernel<<<dim3(SEQ / 64, BSZ * NH), blk, 0, stream>>>(qkvb + 2 * HS, VTg, QKV_STRIDE);

  attention_mfma_kernel<<<dim3(SEQ / 128, NH, BSZ), dim3(128), 0, stream>>>(
      qkvb, qkvb + HS, VTg, mask, attnb);

  // Wo split-K=2: slabs adjacent at 13-29M
  gemm_bf16_kernel<64, 128, false, false, true><<<dim3(8, 64, 2), blk, 0, stream>>>(
      attnb, Wot, nullptr, woP, MROWS, HS, HS, HS / 2, SLAB);
  add_ln_red_kernel<true><<<dim3(MROWS), blk, 0, stream>>>(
      woP, woP + SLAB, bo, x, g1, be1, h, hb);

  gemm_bf16_kernel<128, 128, true, true, false><<<dim3(32, 32), blk, 0, stream>>>(
      hb, W1t, b1, ff1o, MROWS, FF, HS, HS, 0);
  // FF2 split-K=2, 128x128 tile; slab1 via explicit zstride (round-5 bug fix)
  gemm_bf16_kernel<128, 128, false, false, true><<<dim3(8, 32, 2), blk, 0, stream>>>(
      ff1o, W2t, nullptr, ff2P0, MROWS, HS, FF, FF / 2, (size_t)(ff2P1 - ff2P0));
  add_ln_red_kernel<false><<<dim3(MROWS), blk, 0, stream>>>(
      ff2P0, ff2P1, b2, h, g2, be2, out, nullptr);
}